// Round 7
// baseline (322.599 us; speedup 1.0000x reference)
//
#include <hip/hip_runtime.h>

// LSTM: B=4096, T=1024, I=8, H=4. fp32.
// R7: multi-pair wave specialization for latency hiding.
// Evidence: R4->R6 showed the consumer is pinned at ~275 cyc/step by the
// recurrence loop latency (~170cyc) + exposed single-wave stalls; issue- and
// chain-level micro-fixes (R5 batching, R6 Pade) were all neutral/negative.
// Fix: 512-thread blocks = 4 producer waves + 4 consumer waves (4 independent
// 16-stream pairs). Wave->SIMD round-robin puts producer_i + consumer_i on
// SIMD i: producer issue (~75cyc/step) fills the consumer's stall cycles.
// Grid = B/64 = 64 blocks; all 4096 sequences still in flight.
//  - xs: single-buffered 32-step staging per pair (producer is sole client;
//    DMA refill issued a full 8-step round (~1600cyc) before its vmcnt wait,
//    > 900cyc HBM latency).
//  - pa: ping-pong 8-step pre-act chunks; one __syncthreads per 8 steps.
//  - consumer math: exp2-domain gates (R5's, absmax 0.0), fewest issue slots.
// LDS: 66.5KB xs + 65.5KB pa = 132KB (<160KB, 1 block/CU).

#define TT 1024
#define II 8
#define SCH 32               // staging chunk (steps) per xs fill
#define PCH 8                // pre-act chunk (steps) per pa buffer
#define NROUND (TT / PCH)    // 128
#define ROW (SCH * II)       // 256 floats x per stream per staging
#define SPAD 4

#define L2E 1.4426950408889634f
#define SIG_SCALE (-L2E)      // i,f,o rows: sig via rcp(1+exp2(z'))
#define G_SCALE (2.0f * L2E)  // g row: tanh via 1-2*rcp(1+exp2(z'))

typedef float v2f __attribute__((ext_vector_type(2)));

template <int CTRL>
__device__ __forceinline__ float dppf(float v) {
  return __int_as_float(
      __builtin_amdgcn_mov_dpp(__float_as_int(v), CTRL, 0xF, 0xF, true));
}

__device__ __forceinline__ float ex2(float x) {
  return __builtin_amdgcn_exp2f(x);
}
__device__ __forceinline__ float rcp(float x) {
  return __builtin_amdgcn_rcpf(x);
}

#define GLOAD_LDS16(gp, lp)                                   \
  __builtin_amdgcn_global_load_lds(                           \
      (const __attribute__((address_space(1))) void*)(gp),    \
      (__attribute__((address_space(3))) void*)(lp), 16, 0, 0)

__global__ __launch_bounds__(512, 1) void lstm_fused(
    const float* __restrict__ x, const float* __restrict__ W_ih,
    const float* __restrict__ W_hh, const float* __restrict__ b_ih,
    const float* __restrict__ b_hh, const float* __restrict__ fc_w,
    const float* __restrict__ fc_b, float* __restrict__ out, int B) {
  const int tid = threadIdx.x;
  const int wv = tid >> 6;    // 0..7
  const int role = wv >> 2;   // 0: producer, 1: consumer
  const int p = wv & 3;       // pair id; waves p and p+4 share SIMD p
  const int lane = tid & 63;
  const int j = lane & 3;     // owned hidden index
  const int grp = lane >> 2;  // stream within pair
  const int b = blockIdx.x * 64 + p * 16 + grp;

  __shared__ float xs[4][16][ROW + SPAD];       // 66.6 KB
  __shared__ float pa[4][2][PCH][16][16];       // 65.5 KB

  if (role == 0) {
    // ---------------- producer (pair p) ----------------
    v2f wih01[II], wih23[II];
    v2f bias01, bias23;
#pragma unroll
    for (int k = 0; k < II; ++k) {
      wih01[k] = v2f{SIG_SCALE * W_ih[(0 * 4 + j) * II + k],
                     SIG_SCALE * W_ih[(1 * 4 + j) * II + k]};
      wih23[k] = v2f{G_SCALE * W_ih[(2 * 4 + j) * II + k],
                     SIG_SCALE * W_ih[(3 * 4 + j) * II + k]};
    }
    bias01 = v2f{SIG_SCALE * (b_ih[0 * 4 + j] + b_hh[0 * 4 + j]),
                 SIG_SCALE * (b_ih[1 * 4 + j] + b_hh[1 * 4 + j])};
    bias23 = v2f{G_SCALE * (b_ih[2 * 4 + j] + b_hh[2 * 4 + j]),
                 SIG_SCALE * (b_ih[3 * 4 + j] + b_hh[3 * 4 + j])};

    const size_t sbase = (size_t)blockIdx.x * 64 + (size_t)p * 16;

    // Stage 32 steps x 16 streams: 16 instrs, 1KB contiguous per stream.
    auto issue = [&](int t0) {
#pragma unroll
      for (int s = 0; s < 16; ++s) {
        size_t si = sbase + s;
        si = (si < (size_t)B) ? si : (size_t)(B - 1);
        const float* gp = x + si * (TT * II) + (size_t)t0 * II + lane * 4;
        GLOAD_LDS16(gp, &xs[p][s][0]);
      }
    };

    // Project PCH steps starting at float-offset `off` in the staged rows.
    auto produce = [&](float(*pab)[16][16], int off) {
      const float* row = &xs[p][grp][off];
#pragma unroll
      for (int u = 0; u < PCH; ++u) {
        const float4 xa = *(const float4*)(row + u * 8);
        const float4 xb = *(const float4*)(row + u * 8 + 4);
        v2f a01 = bias01, a23 = bias23;
#define XFMA(k, val)                                    \
  {                                                     \
    v2f xv = v2f{(val), (val)};                         \
    a01 = __builtin_elementwise_fma(wih01[k], xv, a01); \
    a23 = __builtin_elementwise_fma(wih23[k], xv, a23); \
  }
        XFMA(0, xa.x) XFMA(1, xa.y) XFMA(2, xa.z) XFMA(3, xa.w)
        XFMA(4, xb.x) XFMA(5, xb.y) XFMA(6, xb.z) XFMA(7, xb.w)
#undef XFMA
        *(float4*)&pab[u][grp][j * 4] = float4{a01.x, a01.y, a23.x, a23.y};
      }
    };

    issue(0);                  // steps [0,32)
    produce(pa[p][0], 0);      // chunk 0 (vmcnt wait: startup only)
    __syncthreads();

    for (int m = 0; m < NROUND; ++m) {
      const int c = m + 1;  // chunk produced this round
      if (c < NROUND) {
        produce(pa[p][c & 1], (c & 3) * (PCH * II));
        // Finished last chunk of the staged 32 steps -> refill for the next
        // 32. Needed when producing chunk c+1 next round (~1600cyc away).
        if ((c & 3) == 3 && c + 1 < NROUND) issue((c + 1) * PCH);
      }
      __syncthreads();
    }
  } else {
    // ---------------- consumer (pair p, serial scan) ----------------
    v2f whh01[4], whh23[4];
#pragma unroll
    for (int k = 0; k < 4; ++k) {
      whh01[k] = v2f{SIG_SCALE * W_hh[(0 * 4 + j) * 4 + k],
                     SIG_SCALE * W_hh[(1 * 4 + j) * 4 + k]};
      whh23[k] = v2f{G_SCALE * W_hh[(2 * 4 + j) * 4 + k],
                     SIG_SCALE * W_hh[(3 * 4 + j) * 4 + k]};
    }
    float h = 0.0f, c2 = 0.0f;  // c2 = 2*log2e * c

    auto step = [&](float4 g) {
      const float h0 = dppf<0x00>(h);
      const float h1 = dppf<0x55>(h);
      const float h2 = dppf<0xAA>(h);
      const float h3 = dppf<0xFF>(h);
      v2f a01 = v2f{g.x, g.y};
      v2f a23 = v2f{g.z, g.w};
#define HFMA(k, val)                                    \
  {                                                     \
    v2f hv = v2f{(val), (val)};                         \
    a01 = __builtin_elementwise_fma(whh01[k], hv, a01); \
    a23 = __builtin_elementwise_fma(whh23[k], hv, a23); \
  }
      HFMA(0, h0) HFMA(1, h1) HFMA(2, h2) HFMA(3, h3)
#undef HFMA
      const float ig = rcp(1.0f + ex2(a01.x));               // sig(i)
      const float fg = rcp(1.0f + ex2(a01.y));               // sig(f)
      const float rg = rcp(1.0f + ex2(a23.x));               // (1-tanh g)/2
      const float og = rcp(1.0f + ex2(a23.y));               // sig(o)
      const float gg2 = fmaf(rg, -2.0f * G_SCALE, G_SCALE);  // 2log2e*tanh(g)
      c2 = fmaf(fg, c2, ig * gg2);
      const float rc = rcp(1.0f + ex2(c2));                  // (1-tanh c)/2
      h = fmaf(rc, -2.0f * og, og);                          // og*tanh(c)
    };

    __syncthreads();

    for (int m = 0; m < NROUND; ++m) {
      const float(*pab)[16][16] = pa[p][m & 1];
      const float* base = &pab[0][grp][j * 4];
      float4 g = *(const float4*)base;
#pragma unroll
      for (int u = 0; u < PCH; ++u) {
        const int un = (u + 1 < PCH) ? (u + 1) : u;  // clamp tail
        const float4 gn = *(const float4*)(base + un * 256);
        step(g);
        g = gn;
      }
      __syncthreads();
    }

    // final FC: out[b] = sum_j h_j * fc_w[j] + fc_b
    float v = h * fc_w[j];
    v += dppf<0xB1>(v);  // quad_perm [1,0,3,2]
    v += dppf<0x4E>(v);  // quad_perm [2,3,0,1]
    if (j == 0 && b < B) out[b] = v + fc_b[0];
  }
}

extern "C" void kernel_launch(void* const* d_in, const int* in_sizes, int n_in,
                              void* d_out, int out_size, void* d_ws,
                              size_t ws_size, hipStream_t stream) {
  const float* x = (const float*)d_in[0];
  const float* W_ih = (const float*)d_in[1];
  const float* W_hh = (const float*)d_in[2];
  const float* b_ih = (const float*)d_in[3];
  const float* b_hh = (const float*)d_in[4];
  const float* fc_w = (const float*)d_in[5];
  const float* fc_b = (const float*)d_in[6];
  float* out = (float*)d_out;

  const int B = in_sizes[0] / (TT * II);
  const int nblocks = (B + 63) / 64;
  lstm_fused<<<nblocks, 512, 0, stream>>>(x, W_ih, W_hh, b_ih, b_hh, fc_w,
                                          fc_b, out, B);
}

// Round 8
// 269.887 us; speedup vs baseline: 1.1953x; 1.1953x over previous
//
#include <hip/hip_runtime.h>

// LSTM: B=4096, T=1024, I=8, H=4. fp32.
// R8: 16 lanes per sequence — gate-parallel layout.
// Evidence R4-R7: any structure where one lane serially computes 4 gates ->
// 4 dependent activations pins at ~275cyc/step; issue- and algebra-level
// fixes invisible; and only 256/1024 SIMDs were populated.
// New mapping: 16-lane group per sequence; lane j*4+q owns gate row q*4+j
// (q=0..3 -> i,f,g,o; j = hidden idx). All 16 gate pre-acts + activations
// run in PARALLEL (one exp2+rcp per lane per step).
//   - h-broadcast across quads: mov_dpp row_ror:4/8/12; source-lane mapping
//     probed at init (direction-proof) and folded into the per-lane W_hh
//     permutation.
//   - gate gather (i,f,g,o of hidden j): quad_perm broadcasts (exact).
//   - per-gate activation made uniform: weights/bias pre-scaled (-log2e for
//     i,f,o; +2log2e for g), act = fma(rcp(1+exp2(a)), A_q, B_q) with
//     per-lane A,B. c carried as c2 = 2log2e*c (R5 math, absmax was 0.0).
// 1024 waves (4 seq/wave) = 1 wave/SIMD on all 256 CUs. Each wave stages its
// own x via global_load_lds (32-step chunks, distinct A/B LDS objects),
// NO barriers anywhere.

#define TT 1024
#define II 8
#define NSC 32  // 32-step staging chunks

#define L2E 1.4426950408889634f
#define SIG_SCALE (-L2E)
#define G_SCALE (2.0f * L2E)

template <int CTRL>
__device__ __forceinline__ float dppf(float v) {
  return __int_as_float(
      __builtin_amdgcn_mov_dpp(__float_as_int(v), CTRL, 0xF, 0xF, true));
}
template <int CTRL>
__device__ __forceinline__ int dppi(int v) {
  return __builtin_amdgcn_mov_dpp(v, CTRL, 0xF, 0xF, true);
}
template <int OFF>
__device__ __forceinline__ float swzf(float v) {
  return __int_as_float(__builtin_amdgcn_ds_swizzle(__float_as_int(v), OFF));
}
__device__ __forceinline__ float ex2(float x) {
  return __builtin_amdgcn_exp2f(x);
}
__device__ __forceinline__ float rcp(float x) {
  return __builtin_amdgcn_rcpf(x);
}

#define GLOAD_LDS16(gp, lp)                                   \
  __builtin_amdgcn_global_load_lds(                           \
      (const __attribute__((address_space(1))) void*)(gp),    \
      (__attribute__((address_space(3))) void*)(lp), 16, 0, 0)

__global__ __launch_bounds__(64, 1) void lstm_fused(
    const float* __restrict__ x, const float* __restrict__ W_ih,
    const float* __restrict__ W_hh, const float* __restrict__ b_ih,
    const float* __restrict__ b_hh, const float* __restrict__ fc_w,
    const float* __restrict__ fc_b, float* __restrict__ out, int B) {
  const int lane = threadIdx.x;  // one wave per block
  const int sg = lane >> 4;      // sequence within wave (0..3)
  const int sl = lane & 15;      // lane within 16-group
  const int j = sl >> 2;         // hidden index (quad id)
  const int q = sl & 3;          // gate type: 0=i,1=f,2=g,3=o
  const int r = q * 4 + j;       // PyTorch gate-row index
  const int seq = blockIdx.x * 4 + sg;
  const int sq = (seq < B) ? seq : (B - 1);

  const float scale = (q == 2) ? G_SCALE : SIG_SCALE;
  const float actA = (q == 2) ? (-2.0f * G_SCALE) : 1.0f;  // g: 2log2e*tanh
  const float actB = (q == 2) ? G_SCALE : 0.0f;            // i,f,o: sigmoid

  float wih[II];
#pragma unroll
  for (int k = 0; k < II; ++k) wih[k] = scale * W_ih[r * II + k];
  const float bias = scale * (b_ih[r] + b_hh[r]);

  // Probe row_ror source mapping once (direction-proof): js* = hidden index
  // whose h arrives on this lane under each rotation; index W_hh with it.
  const int js4 = (dppi<0x124>(sl) >> 2) & 3;   // row_ror:4
  const int js8 = (dppi<0x128>(sl) >> 2) & 3;   // row_ror:8
  const int js12 = (dppi<0x12C>(sl) >> 2) & 3;  // row_ror:12
  const float wh0 = scale * W_hh[r * 4 + j];
  const float wh1 = scale * W_hh[r * 4 + js4];
  const float wh2 = scale * W_hh[r * 4 + js8];
  const float wh3 = scale * W_hh[r * 4 + js12];

  // x staging: [span m][seq][64 floats] = 8 steps per DMA instr (1KB).
  __shared__ float xsA[4][4][64];
  __shared__ float xsB[4][4][64];

  const float* xbase = x + (size_t)sq * (TT * II);

  auto issueA = [&](int t0) {
#pragma unroll
    for (int m = 0; m < 4; ++m)
      GLOAD_LDS16(xbase + (t0 + m * 8) * II + sl * 4, &xsA[m][0][0]);
  };
  auto issueB = [&](int t0) {
#pragma unroll
    for (int m = 0; m < 4; ++m)
      GLOAD_LDS16(xbase + (t0 + m * 8) * II + sl * 4, &xsB[m][0][0]);
  };

  float h = 0.0f, c2 = 0.0f;  // c2 = 2*log2e*c, replicated across quad

  auto step = [&](const float* xr) {
    // x-projection: off the serial chain (8 indep FMAs; 16-lane broadcast
    // ds_read, same addr within group -> LDS broadcast).
    const float4 xa = *(const float4*)xr;
    const float4 xb = *(const float4*)(xr + 4);
    float a = bias;
    a = fmaf(wih[0], xa.x, a);
    a = fmaf(wih[1], xa.y, a);
    a = fmaf(wih[2], xa.z, a);
    a = fmaf(wih[3], xa.w, a);
    a = fmaf(wih[4], xb.x, a);
    a = fmaf(wih[5], xb.y, a);
    a = fmaf(wih[6], xb.z, a);
    a = fmaf(wih[7], xb.w, a);
    // serial chain
    const float r4 = dppf<0x124>(h);
    const float r8 = dppf<0x128>(h);
    const float r12 = dppf<0x12C>(h);
    a = fmaf(wh0, h, a);
    a = fmaf(wh1, r4, a);
    a = fmaf(wh2, r8, a);
    a = fmaf(wh3, r12, a);
    const float act = fmaf(rcp(1.0f + ex2(a)), actA, actB);
    const float gi = dppf<0x00>(act);  // i_j -> whole quad
    const float gf = dppf<0x55>(act);  // f_j
    const float gg = dppf<0xAA>(act);  // 2log2e*tanh(g_j)
    const float go = dppf<0xFF>(act);  // o_j
    c2 = fmaf(gf, c2, gi * gg);
    const float rc = rcp(1.0f + ex2(c2));  // (1-tanh c)/2
    h = fmaf(rc, -2.0f * go, go);          // o*tanh(c)
  };

  issueA(0);
  issueB(NSC);

  for (int sc = 0; sc < TT / NSC; ++sc) {
    const float* xs = (sc & 1) ? &xsB[0][0][0] : &xsA[0][0][0];
    const float* grow = xs + sg * 64;
#pragma unroll
    for (int m = 0; m < 4; ++m) {
#pragma unroll
      for (int u = 0; u < 8; ++u) step(grow + m * 256 + u * 8);
    }
    // Refill the buffer just consumed (WAR-safe: its reads completed on the
    // chain; DMA lands >=900cyc later). Other buffer's DMA is ~4000cyc old
    // when read next iter.
    if (sc + 2 < TT / NSC) {
      if (sc & 1)
        issueB((sc + 2) * NSC);
      else
        issueA((sc + 2) * NSC);
    }
  }

  // Final FC: every lane holds h_j (replicated in quad). Sum over quads via
  // self-inverse ds_swizzle xor-4/8, then out = sum_j h_j*fc_w[j] + fc_b.
  float v = h * fc_w[j];
  v += swzf<0x101F>(v);  // xor 4: quad j <-> j^1
  v += swzf<0x201F>(v);  // xor 8: + quads j^2
  if (sl == 0 && seq < B) out[seq] = v + fc_b[0];
}

extern "C" void kernel_launch(void* const* d_in, const int* in_sizes, int n_in,
                              void* d_out, int out_size, void* d_ws,
                              size_t ws_size, hipStream_t stream) {
  const float* x = (const float*)d_in[0];
  const float* W_ih = (const float*)d_in[1];
  const float* W_hh = (const float*)d_in[2];
  const float* b_ih = (const float*)d_in[3];
  const float* b_hh = (const float*)d_in[4];
  const float* fc_w = (const float*)d_in[5];
  const float* fc_b = (const float*)d_in[6];
  float* out = (float*)d_out;

  const int B = in_sizes[0] / (TT * II);
  const int nblocks = (B + 3) / 4;
  lstm_fused<<<nblocks, 64, 0, stream>>>(x, W_ih, W_hh, b_ih, b_hh, fc_w,
                                         fc_b, out, B);
}